// Round 3
// baseline (3301.885 us; speedup 1.0000x reference)
//
#include <hip/hip_runtime.h>
#include <cstdint>
#include <cstddef>

typedef unsigned short u16;
typedef float f32x4 __attribute__((ext_vector_type(4)));
typedef short s16x8 __attribute__((ext_vector_type(8)));
typedef unsigned short u16x4 __attribute__((ext_vector_type(4)));
typedef __bf16 bf16x8 __attribute__((ext_vector_type(8)));

#define DEV static __device__ __forceinline__

DEV u16 f2bf(float f) {
  uint32_t x = __float_as_uint(f);
  return (u16)((x + 0x7fffu + ((x >> 16) & 1u)) >> 16);  // RNE
}
DEV float bf2f(u16 u) { return __uint_as_float(((uint32_t)u) << 16); }

DEV f32x4 mfma16(bf16x8 a, bf16x8 b, f32x4 c) {
  return __builtin_amdgcn_mfma_f32_16x16x32_bf16(a, b, c, 0, 0, 0);
}

DEV uint32_t pkbf(float lo, float hi) {
  uint32_t r;
  asm("v_cvt_pk_bf16_f32 %0, %1, %2" : "=v"(r) : "v"(lo), "v"(hi));
  return r;
}

typedef __attribute__((address_space(1))) const uint32_t gu32;
typedef __attribute__((address_space(3))) uint32_t lu32;
DEV void gload16(const u16* g, u16* l) {
  __builtin_amdgcn_global_load_lds((gu32*)g, (lu32*)l, 16, 0, 0);
}

// ---------------- copy x_cls -> d_out ----------------
__global__ __launch_bounds__(256) void k_copy(const float* __restrict__ src,
                                              float* __restrict__ dst, int n4) {
  int i = blockIdx.x * blockDim.x + threadIdx.x;
  const float4* s = (const float4*)src;
  float4* d = (float4*)dst;
  for (; i < n4; i += gridDim.x * blockDim.x) d[i] = s[i];
}

// ---------------- fp32 -> bf16 cast (proj/fc2 weights) ----------------
__global__ __launch_bounds__(256) void k_cast4(const float* __restrict__ src,
                                               u16* __restrict__ dst, int n4) {
  int i = blockIdx.x * blockDim.x + threadIdx.x;
  for (; i < n4; i += gridDim.x * blockDim.x) {
    float4 v = ((const float4*)src)[i];
    u16x4 o;
    o[0] = f2bf(v.x); o[1] = f2bf(v.y); o[2] = f2bf(v.z); o[3] = f2bf(v.w);
    ((u16x4*)dst)[i] = o;
  }
}

// ---------------- Weight fold: Wout = W .* lw (bf16); bout = b0 + W @ lb ----------------
__global__ __launch_bounds__(256) void k_fold(const float* __restrict__ W,
                                              const float* __restrict__ lw,
                                              const float* __restrict__ lb,
                                              const float* __restrict__ b0,
                                              u16* __restrict__ Wout,
                                              float* __restrict__ bout, int nrows) {
  int wv = blockIdx.x * 4 + (threadIdx.x >> 6), lane = threadIdx.x & 63;
  if (wv >= nrows) return;
  float4 w4 = ((const float4*)(W + (size_t)wv * 256))[lane];
  float4 s4 = ((const float4*)lw)[lane];
  float4 t4 = ((const float4*)lb)[lane];
  u16x4 o;
  o[0] = f2bf(w4.x * s4.x); o[1] = f2bf(w4.y * s4.y);
  o[2] = f2bf(w4.z * s4.z); o[3] = f2bf(w4.w * s4.w);
  ((u16x4*)(Wout + (size_t)wv * 256))[lane] = o;
  float d = w4.x * t4.x + w4.y * t4.y + w4.z * t4.z + w4.w * t4.w;
#pragma unroll
  for (int m = 1; m < 64; m <<= 1) d += __shfl_xor(d, m, 64);
  if (lane == 0) bout[wv] = (b0 ? b0[wv] : 0.f) + d;
}

// ---------------- Pure normalize (LN without affine; affine folded into weights) ----------
// mode 0: cls rows: src=xc[4800][256] -> scatter nx[b*2100+t] AND compact comp[wv]
// mode 1: patch rows: src=x_patch[129600][256] -> scatter nx[b*2100+75+p]
// mode 2: rows: src[ntok][256] -> compact comp only
__global__ __launch_bounds__(256) void k_norm(const float* __restrict__ src,
                                              u16* __restrict__ scat,
                                              u16* __restrict__ comp,
                                              int mode, int ntok) {
  int wv = blockIdx.x * 4 + (threadIdx.x >> 6), lane = threadIdx.x & 63;
  if (wv >= ntok) return;
  float4 v = ((const float4*)(src + (size_t)wv * 256))[lane];
  float s = v.x + v.y + v.z + v.w;
  float q = v.x * v.x + v.y * v.y + v.z * v.z + v.w * v.w;
#pragma unroll
  for (int m = 1; m < 64; m <<= 1) {
    s += __shfl_xor(s, m, 64);
    q += __shfl_xor(q, m, 64);
  }
  float mean = s * (1.f / 256.f);
  float var = q * (1.f / 256.f) - mean * mean;
  float rstd = rsqrtf(var + 1e-5f);
  u16x4 o;
  o[0] = f2bf((v.x - mean) * rstd);
  o[1] = f2bf((v.y - mean) * rstd);
  o[2] = f2bf((v.z - mean) * rstd);
  o[3] = f2bf((v.w - mean) * rstd);
  if (mode == 0) {
    int b = wv / 75, t = wv - b * 75;
    ((u16x4*)(scat + (size_t)(b * 2100 + t) * 256))[lane] = o;
    ((u16x4*)(comp + (size_t)wv * 256))[lane] = o;
  } else if (mode == 1) {
    int b = wv / 2025, p = wv - b * 2025;
    ((u16x4*)(scat + (size_t)(b * 2100 + 75 + p) * 256))[lane] = o;
  } else {
    ((u16x4*)(comp + (size_t)wv * 256))[lane] = o;
  }
}

// ---------------- Unified MFMA GEMM: C[M,N] = A[M,K] @ Bw[N,K]^T + bias ----------------
// 128x256 tile, 256 thr / 4 waves, wave-tile 64x128; global_load_lds staging, dbuf LDS.
// Requires N % 256 == 0 (grid.y = N/256), K % 32 == 0.
// modes: 0 = kv plane store bf16: obf[((n>>5)*M + m)*32 + (n&31)] = v + bias
//        1 = obf[m*N+n] = bf16((v + bias) * scale)
//        2 = of32[m*N+n] += gamma[n] * (v + bias[n])
//        3 = obf[m*N+n] = bf16(gelu(v + bias[n]))
__global__ __launch_bounds__(256) void k_gemm2(const u16* __restrict__ A,
                                               const u16* __restrict__ Bw,
                                               int M, int N, int K, int mode, float scale,
                                               const float* __restrict__ bias,
                                               const float* __restrict__ gamma,
                                               u16* __restrict__ obf,
                                               float* __restrict__ of32) {
  __shared__ u16 sA[2][4096];   // [128][32] per buf
  __shared__ u16 sB[2][8192];   // [256][32] per buf
  const int tid = threadIdx.x, lane = tid & 63, w = tid >> 6;
  const int l15 = lane & 15, g = lane >> 4;
  const int wm = w >> 1, wn = w & 1;
  const int m0 = blockIdx.x * 128, n0 = blockIdx.y * 256;
  const int rl = lane >> 2, sg0 = lane & 3;

  const u16* aS[2];
  const u16* bS[4];
#pragma unroll
  for (int a = 0; a < 2; a++) {
    int r = m0 + 32 * w + 16 * a + rl;
    if (r > M - 1) r = M - 1;
    aS[a] = A + (size_t)r * K + sg0 * 8;
  }
#pragma unroll
  for (int c = 0; c < 4; c++) {
    int n = n0 + 64 * w + 16 * c + rl;
    bS[c] = Bw + (size_t)n * K + sg0 * 8;
  }

  f32x4 acc[4][8] = {};
  const int nks = K >> 5;

#pragma unroll
  for (int a = 0; a < 2; a++) gload16(aS[a], &sA[0][w * 1024 + a * 512]);
#pragma unroll
  for (int c = 0; c < 4; c++) gload16(bS[c], &sB[0][w * 2048 + c * 512]);

  int cur = 0;
  for (int ks = 0; ks < nks; ks++) {
    __syncthreads();  // drains vmcnt: tile `cur` ready; prev reads done
    if (ks + 1 < nks) {
      int k0 = 32 * (ks + 1);
#pragma unroll
      for (int a = 0; a < 2; a++) gload16(aS[a] + k0, &sA[cur ^ 1][w * 1024 + a * 512]);
#pragma unroll
      for (int c = 0; c < 4; c++) gload16(bS[c] + k0, &sB[cur ^ 1][w * 2048 + c * 512]);
    }
    s16x8 af[4], bfr[8];
#pragma unroll
    for (int i = 0; i < 4; i++) {
      int r = wm * 64 + i * 16 + l15;
      af[i] = *(const s16x8*)&sA[cur][r * 32 + g * 8];
    }
#pragma unroll
    for (int j = 0; j < 8; j++) {
      int n = wn * 128 + j * 16 + l15;
      bfr[j] = *(const s16x8*)&sB[cur][n * 32 + g * 8];
    }
#pragma unroll
    for (int i = 0; i < 4; i++)
#pragma unroll
      for (int j = 0; j < 8; j++)
        acc[i][j] = mfma16(__builtin_bit_cast(bf16x8, af[i]),
                           __builtin_bit_cast(bf16x8, bfr[j]), acc[i][j]);
    cur ^= 1;
  }

#pragma unroll
  for (int i = 0; i < 4; i++) {
#pragma unroll
    for (int j = 0; j < 8; j++) {
      int gmBase = m0 + wm * 64 + i * 16 + g * 4;
      int gn = n0 + wn * 128 + j * 16 + l15;
      float bs = bias[gn];
#pragma unroll
      for (int r = 0; r < 4; r++) {
        int gm = gmBase + r;
        if (gm >= M) continue;
        float v = acc[i][j][r] + bs;
        if (mode == 0) {
          obf[((size_t)(gn >> 5) * M + gm) * 32 + (gn & 31)] = f2bf(v);
        } else if (mode == 1) {
          obf[(size_t)gm * N + gn] = f2bf(v * scale);
        } else if (mode == 2) {
          of32[(size_t)gm * N + gn] += gamma[gn] * v;
        } else {
          obf[(size_t)gm * N + gn] = f2bf(0.5f * v * (1.f + erff(v * 0.70710678118654752f)));
        }
      }
    }
  }
}

// ---------------- MFMA flash attention (unchanged from R2) ----------------
__global__ __launch_bounds__(256) void k_attn(const u16* __restrict__ qb,
                                              const u16* __restrict__ kvb,
                                              u16* __restrict__ obf) {
  __shared__ u16 VtS[4][32][36];
  __shared__ uint32_t Pbuf[4][16][20];
  __shared__ float maccS[4][2560];
  __shared__ float mlS[4][160];

  const int bid = blockIdx.x;
  const int b = bid & 63, h = bid >> 6;
  const int tid = threadIdx.x, lane = tid & 63, w = tid >> 6;
  const int l15 = lane & 15, g = lane >> 4;

  const u16* Kp = kvb + ((size_t)h * 134400 + (size_t)b * 2100) * 32;
  const u16* Vp = kvb + ((size_t)(8 + h) * 134400 + (size_t)b * 2100) * 32;

  bf16x8 bq[5];
#pragma unroll
  for (int qt = 0; qt < 5; qt++) {
    int q = qt * 16 + l15; if (q > 74) q = 74;
    s16x8 qv = *(const s16x8*)(qb + (size_t)(b * 75 + q) * 256 + h * 32 + g * 8);
    bq[qt] = __builtin_bit_cast(bf16x8, qv);
  }

  f32x4 acc[5][2] = {};
  float mlc[5], llc[5];
#pragma unroll
  for (int qt = 0; qt < 5; qt++) { mlc[qt] = -1e30f; llc[qt] = 0.f; }

  s16x8 kfA, kfB, vvA, vvB;
  {
    int t0 = w * 32;
    int ta = t0 + l15; if (ta > 2099) ta = 2099;
    int tb = t0 + 16 + l15; if (tb > 2099) tb = 2099;
    kfA = *(const s16x8*)(Kp + (size_t)ta * 32 + g * 8);
    kfB = *(const s16x8*)(Kp + (size_t)tb * 32 + g * 8);
    int tga = t0 + (lane >> 2); if (tga > 2099) tga = 2099;
    int tgb = t0 + ((lane + 64) >> 2); if (tgb > 2099) tgb = 2099;
    vvA = *(const s16x8*)(Vp + (size_t)tga * 32 + (lane & 3) * 8);
    vvB = *(const s16x8*)(Vp + (size_t)tgb * 32 + (lane & 3) * 8);
  }

  for (int tt = w; tt < 66; tt += 4) {
    const int t0 = tt * 32;
    {
      u16* d0 = &VtS[w][lane >> 2][(lane & 3) * 8];
      u16* d1 = &VtS[w][(lane + 64) >> 2][(lane & 3) * 8];
#pragma unroll
      for (int e = 0; e < 8; e++) d0[e] = (u16)vvA[e];
#pragma unroll
      for (int e = 0; e < 8; e++) d1[e] = (u16)vvB[e];
    }
    bf16x8 bA = __builtin_bit_cast(bf16x8, kfA);
    bf16x8 bB = __builtin_bit_cast(bf16x8, kfB);
    s16x8 v0, v1;
#pragma unroll
    for (int e = 0; e < 8; e++) {
      v0[e] = (short)VtS[w][8 * g + e][l15];
      v1[e] = (short)VtS[w][8 * g + e][16 + l15];
    }
    bf16x8 bv0 = __builtin_bit_cast(bf16x8, v0);
    bf16x8 bv1 = __builtin_bit_cast(bf16x8, v1);
    int tn = tt + 4;
    if (tn < 66) {
      int t0n = tn * 32;
      int ta = t0n + l15; if (ta > 2099) ta = 2099;
      int tb = t0n + 16 + l15; if (tb > 2099) tb = 2099;
      kfA = *(const s16x8*)(Kp + (size_t)ta * 32 + g * 8);
      kfB = *(const s16x8*)(Kp + (size_t)tb * 32 + g * 8);
      int tga = t0n + (lane >> 2); if (tga > 2099) tga = 2099;
      int tgb = t0n + ((lane + 64) >> 2); if (tgb > 2099) tgb = 2099;
      vvA = *(const s16x8*)(Vp + (size_t)tga * 32 + (lane & 3) * 8);
      vvB = *(const s16x8*)(Vp + (size_t)tgb * 32 + (lane & 3) * 8);
    }
    const bool lastTile = (t0 == 2080);

#pragma unroll
    for (int qt = 0; qt < 5; qt++) {
      f32x4 z = {0.f, 0.f, 0.f, 0.f};
      f32x4 sA = mfma16(bA, bq[qt], z);
      f32x4 sB = mfma16(bB, bq[qt], z);
      if (lastTile && g >= 1) {
        sB[0] = sB[1] = sB[2] = sB[3] = -1e30f;
      }
      float px = fmaxf(fmaxf(fmaxf(sA[0], sA[1]), fmaxf(sA[2], sA[3])),
                       fmaxf(fmaxf(sB[0], sB[1]), fmaxf(sB[2], sB[3])));
      px = fmaxf(px, __shfl_xor(px, 16, 64));
      px = fmaxf(px, __shfl_xor(px, 32, 64));
      float mq = mlc[qt];
      if (!__all(px <= mq + 8.f)) {
        float mn = fmaxf(mq, px);
        float rs = exp2f(mq - mn);
        mlc[qt] = mn;
        llc[qt] *= rs;
#pragma unroll
        for (int r = 0; r < 4; r++) {
          float rr = __shfl(rs, ((lane >> 4) << 2) + r, 64);
          acc[qt][0][r] *= rr;
          acc[qt][1][r] *= rr;
        }
        mq = mn;
      }
      f32x4 pA, pB;
#pragma unroll
      for (int r = 0; r < 4; r++) {
        pA[r] = exp2f(sA[r] - mq);
        pB[r] = exp2f(sB[r] - mq);
      }
      float ps = pA[0] + pA[1] + pA[2] + pA[3] + pB[0] + pB[1] + pB[2] + pB[3];
      ps += __shfl_xor(ps, 16, 64);
      ps += __shfl_xor(ps, 32, 64);
      llc[qt] += ps;
      uint32_t* Pu = &Pbuf[w][l15][0];
      Pu[2 * g]     = pkbf(pA[0], pA[1]);
      Pu[2 * g + 1] = pkbf(pA[2], pA[3]);
      Pu[8 + 2 * g]     = pkbf(pB[0], pB[1]);
      Pu[8 + 2 * g + 1] = pkbf(pB[2], pB[3]);
      uint4 pu = *(const uint4*)&Pbuf[w][l15][4 * g];
      bf16x8 bp = __builtin_bit_cast(bf16x8, pu);
      acc[qt][0] = mfma16(bp, bv0, acc[qt][0]);
      acc[qt][1] = mfma16(bp, bv1, acc[qt][1]);
    }
  }

#pragma unroll
  for (int qt = 0; qt < 5; qt++)
#pragma unroll
    for (int dh = 0; dh < 2; dh++)
#pragma unroll
      for (int r = 0; r < 4; r++) {
        int q = qt * 16 + 4 * g + r;
        maccS[w][q * 32 + dh * 16 + l15] = acc[qt][dh][r];
      }
  if (lane < 16) {
#pragma unroll
    for (int qt = 0; qt < 5; qt++) {
      mlS[w][qt * 16 + l15] = mlc[qt];
      mlS[w][80 + qt * 16 + l15] = llc[qt];
    }
  }
  __syncthreads();

  for (int idx = tid; idx < 2400; idx += 256) {
    int q = idx >> 5, d = idx & 31;
    float M = -1e30f;
#pragma unroll
    for (int ww = 0; ww < 4; ww++) M = fmaxf(M, mlS[ww][q]);
    float L = 0.f, O = 0.f;
#pragma unroll
    for (int ww = 0; ww < 4; ww++) {
      float sc = exp2f(mlS[ww][q] - M);
      L += mlS[ww][80 + q] * sc;
      O += maccS[ww][q * 32 + d] * sc;
    }
    obf[(size_t)(b * 75 + q) * 256 + h * 32 + d] = f2bf(O / L);
  }
}

// ---------------- host ----------------
extern "C" void kernel_launch(void* const* d_in, const int* in_sizes, int n_in,
                              void* d_out, int out_size, void* d_ws, size_t ws_size,
                              hipStream_t stream) {
  const float* x_cls   = (const float*)d_in[0];
  const float* x_patch = (const float*)d_in[1];
  const float* ln1_w   = (const float*)d_in[2];
  const float* ln1_b   = (const float*)d_in[3];
  const float* q_w     = (const float*)d_in[4];
  const float* k_w     = (const float*)d_in[5];
  const float* v_w     = (const float*)d_in[6];
  const float* proj_w  = (const float*)d_in[7];
  const float* proj_b  = (const float*)d_in[8];
  const float* ln2_w   = (const float*)d_in[9];
  const float* ln2_b   = (const float*)d_in[10];
  const float* fc1_w   = (const float*)d_in[11];
  const float* fc1_b   = (const float*)d_in[12];
  const float* fc2_w   = (const float*)d_in[13];
  const float* fc2_b   = (const float*)d_in[14];
  const float* gamma1  = (const float*)d_in[15];
  const float* gamma2  = (const float*)d_in[16];
  float* xc = (float*)d_out;

  char* ws = (char*)d_ws;
  size_t off = 0;
  auto alloc = [&](size_t bytes) {
    char* p = ws + off;
    off += (bytes + 255) & ~(size_t)255;
    return p;
  };
  u16* nx    = (u16*)alloc(134400ull * 256 * 2);   // normalized tokens (no affine)
  u16* uncls = (u16*)alloc(4800ull * 256 * 2);
  u16* kvb   = (u16*)alloc(134400ull * 512 * 2);
  u16* qb    = (u16*)alloc(4800ull * 256 * 2);
  u16* ob    = (u16*)alloc(4800ull * 256 * 2);
  u16* xn    = (u16*)alloc(4800ull * 256 * 2);
  u16* hb    = (u16*)alloc(4800ull * 1024 * 2);
  u16* qp    = (u16*)alloc(2ull * 65536 * 2);
  u16* kvp   = (u16*)alloc(2ull * 131072 * 2);
  u16* pjp   = (u16*)alloc(2ull * 65536 * 2);
  u16* f1p   = (u16*)alloc(2ull * 262144 * 2);
  u16* f2p   = (u16*)alloc(2ull * 262144 * 2);
  float* bias_kv = (float*)alloc(2ull * 512 * 4);
  float* bias_q  = (float*)alloc(2ull * 256 * 4);
  float* bias_f1 = (float*)alloc(2ull * 1024 * 4);

  k_copy<<<1200, 256, 0, stream>>>(x_cls, xc, 307200);
  for (int i = 0; i < 2; i++) {
    k_fold<<<64, 256, 0, stream>>>(k_w + i * 65536, ln1_w + i * 256, ln1_b + i * 256,
                                   nullptr, kvp + i * 131072, bias_kv + i * 512, 256);
    k_fold<<<64, 256, 0, stream>>>(v_w + i * 65536, ln1_w + i * 256, ln1_b + i * 256,
                                   nullptr, kvp + i * 131072 + 65536, bias_kv + i * 512 + 256, 256);
    k_fold<<<64, 256, 0, stream>>>(q_w + i * 65536, ln1_w + i * 256, ln1_b + i * 256,
                                   nullptr, qp + i * 65536, bias_q + i * 256, 256);
    k_fold<<<256, 256, 0, stream>>>(fc1_w + i * 262144, ln2_w + i * 256, ln2_b + i * 256,
                                    fc1_b + i * 1024, f1p + i * 262144, bias_f1 + i * 1024, 1024);
    k_cast4<<<64, 256, 0, stream>>>(proj_w + i * 65536, pjp + i * 65536, 16384);
    k_cast4<<<256, 256, 0, stream>>>(fc2_w + i * 262144, f2p + i * 262144, 65536);
  }
  // normalize patch tokens ONCE (identical across both CA blocks)
  k_norm<<<32400, 256, 0, stream>>>(x_patch, nx, nullptr, 1, 129600);

  const float qscale = 0.25503489f;  // 1/sqrt(32) * log2(e)
  for (int i = 0; i < 2; i++) {
    k_norm<<<1200, 256, 0, stream>>>(xc, nx, uncls, 0, 4800);
    dim3 gkv(1050, 2);
    k_gemm2<<<gkv, 256, 0, stream>>>(nx, kvp + i * 131072, 134400, 512, 256, 0, 0.f,
                                     bias_kv + i * 512, nullptr, kvb, nullptr);
    dim3 gq(38, 1);
    k_gemm2<<<gq, 256, 0, stream>>>(uncls, qp + i * 65536, 4800, 256, 256, 1, qscale,
                                    bias_q + i * 256, nullptr, qb, nullptr);
    k_attn<<<512, 256, 0, stream>>>(qb, kvb, ob);
    k_gemm2<<<gq, 256, 0, stream>>>(ob, pjp + i * 65536, 4800, 256, 256, 2, 0.f,
                                    proj_b + i * 256, gamma1 + i * 256, nullptr, xc);
    k_norm<<<1200, 256, 0, stream>>>(xc, nullptr, xn, 2, 4800);
    dim3 gf1(38, 4);
    k_gemm2<<<gf1, 256, 0, stream>>>(xn, f1p + i * 262144, 4800, 1024, 256, 3, 0.f,
                                     bias_f1 + i * 1024, nullptr, hb, nullptr);
    k_gemm2<<<gq, 256, 0, stream>>>(hb, f2p + i * 262144, 4800, 256, 1024, 2, 0.f,
                                    fc2_b + i * 256, gamma2 + i * 256, nullptr, xc);
  }
}

// Round 4
// 626.426 us; speedup vs baseline: 5.2710x; 5.2710x over previous
//
#include <hip/hip_runtime.h>
#include <cstdint>
#include <cstddef>

typedef unsigned short u16;
typedef float f32x4 __attribute__((ext_vector_type(4)));
typedef short s16x8 __attribute__((ext_vector_type(8)));
typedef unsigned short u16x4 __attribute__((ext_vector_type(4)));
typedef __bf16 bf16x8 __attribute__((ext_vector_type(8)));

#define DEV static __device__ __forceinline__

DEV u16 f2bf(float f) {
  uint32_t x = __float_as_uint(f);
  return (u16)((x + 0x7fffu + ((x >> 16) & 1u)) >> 16);  // RNE
}
DEV float bf2f(u16 u) { return __uint_as_float(((uint32_t)u) << 16); }

DEV f32x4 mfma16(bf16x8 a, bf16x8 b, f32x4 c) {
  return __builtin_amdgcn_mfma_f32_16x16x32_bf16(a, b, c, 0, 0, 0);
}

DEV uint32_t pkbf(float lo, float hi) {
  uint32_t r;
  asm("v_cvt_pk_bf16_f32 %0, %1, %2" : "=v"(r) : "v"(lo), "v"(hi));
  return r;
}

// byte offset in a [128 rows][128 B] LDS tile, XOR-swizzled: bank-uniform for
// both the staging ds_write_b128 (rows e>>3, slots e&7) and the fragment
// ds_read_b128 (rows ..+l15, slots s*4+g). Verified: 8 lanes per 16B slot,
// 8 disjoint slots -> every bank serves exactly 8 accesses = 8-cyc minimum.
DEV int swzb(int row, int boff) { return row * 128 + (boff ^ ((row & 7) << 4)); }

// ---------------- copy x_cls -> d_out ----------------
__global__ __launch_bounds__(256) void k_copy(const float* __restrict__ src,
                                              float* __restrict__ dst, int n4) {
  int i = blockIdx.x * blockDim.x + threadIdx.x;
  const float4* s = (const float4*)src;
  float4* d = (float4*)dst;
  for (; i < n4; i += gridDim.x * blockDim.x) d[i] = s[i];
}

// ---------------- fp32 -> bf16 cast (proj/fc2 weights) ----------------
__global__ __launch_bounds__(256) void k_cast4(const float* __restrict__ src,
                                               u16* __restrict__ dst, int n4) {
  int i = blockIdx.x * blockDim.x + threadIdx.x;
  for (; i < n4; i += gridDim.x * blockDim.x) {
    float4 v = ((const float4*)src)[i];
    u16x4 o;
    o[0] = f2bf(v.x); o[1] = f2bf(v.y); o[2] = f2bf(v.z); o[3] = f2bf(v.w);
    ((u16x4*)dst)[i] = o;
  }
}

// ---------------- Weight fold: Wout = W .* lw (bf16); bout = b0 + W @ lb ----------------
__global__ __launch_bounds__(256) void k_fold(const float* __restrict__ W,
                                              const float* __restrict__ lw,
                                              const float* __restrict__ lb,
                                              const float* __restrict__ b0,
                                              u16* __restrict__ Wout,
                                              float* __restrict__ bout, int nrows) {
  int wv = blockIdx.x * 4 + (threadIdx.x >> 6), lane = threadIdx.x & 63;
  if (wv >= nrows) return;
  float4 w4 = ((const float4*)(W + (size_t)wv * 256))[lane];
  float4 s4 = ((const float4*)lw)[lane];
  float4 t4 = ((const float4*)lb)[lane];
  u16x4 o;
  o[0] = f2bf(w4.x * s4.x); o[1] = f2bf(w4.y * s4.y);
  o[2] = f2bf(w4.z * s4.z); o[3] = f2bf(w4.w * s4.w);
  ((u16x4*)(Wout + (size_t)wv * 256))[lane] = o;
  float d = w4.x * t4.x + w4.y * t4.y + w4.z * t4.z + w4.w * t4.w;
#pragma unroll
  for (int m = 1; m < 64; m <<= 1) d += __shfl_xor(d, m, 64);
  if (lane == 0) bout[wv] = (b0 ? b0[wv] : 0.f) + d;
}

// ---------------- Pure normalize (affine folded into weights) ----------
__global__ __launch_bounds__(256) void k_norm(const float* __restrict__ src,
                                              u16* __restrict__ scat,
                                              u16* __restrict__ comp,
                                              int mode, int ntok) {
  int wv = blockIdx.x * 4 + (threadIdx.x >> 6), lane = threadIdx.x & 63;
  if (wv >= ntok) return;
  float4 v = ((const float4*)(src + (size_t)wv * 256))[lane];
  float s = v.x + v.y + v.z + v.w;
  float q = v.x * v.x + v.y * v.y + v.z * v.z + v.w * v.w;
#pragma unroll
  for (int m = 1; m < 64; m <<= 1) {
    s += __shfl_xor(s, m, 64);
    q += __shfl_xor(q, m, 64);
  }
  float mean = s * (1.f / 256.f);
  float var = q * (1.f / 256.f) - mean * mean;
  float rstd = rsqrtf(var + 1e-5f);
  u16x4 o;
  o[0] = f2bf((v.x - mean) * rstd);
  o[1] = f2bf((v.y - mean) * rstd);
  o[2] = f2bf((v.z - mean) * rstd);
  o[3] = f2bf((v.w - mean) * rstd);
  if (mode == 0) {
    int b = wv / 75, t = wv - b * 75;
    ((u16x4*)(scat + (size_t)(b * 2100 + t) * 256))[lane] = o;
    ((u16x4*)(comp + (size_t)wv * 256))[lane] = o;
  } else if (mode == 1) {
    int b = wv / 2025, p = wv - b * 2025;
    ((u16x4*)(scat + (size_t)(b * 2100 + 75 + p) * 256))[lane] = o;
  } else {
    ((u16x4*)(comp + (size_t)wv * 256))[lane] = o;
  }
}

// ---------------- MFMA GEMM: C[M,N] = A[M,K] @ Bw[N,K]^T + bias ----------------
// 128x128 tile, 4 waves (2x2), BK=64, reg-staged pipeline, raw barriers,
// XOR-swizzled single-buffered LDS. Requires N%128==0, K%64==0.
// modes: 0 = kv plane store bf16: obf[((n>>5)*M + m)*32 + (n&31)]
//        1 = obf[m*N+n] = bf16(v*scale)
//        2 = of32[m*N+n] += gamma[n]*v
//        3 = obf[m*N+n] = bf16(gelu(v))
__global__ __launch_bounds__(256) void k_gemm3(const u16* __restrict__ A,
                                               const u16* __restrict__ Bw,
                                               int M, int N, int K, int mode, float scale,
                                               const float* __restrict__ bias,
                                               const float* __restrict__ gamma,
                                               u16* __restrict__ obf,
                                               float* __restrict__ of32) {
  __shared__ __align__(16) char smA[16384];   // [128][64] u16, swizzled rows
  __shared__ __align__(16) char smB[16384];
  const int tid = threadIdx.x, lane = tid & 63, w = tid >> 6;
  const int l15 = lane & 15, g = lane >> 4;
  const int wm = w >> 1, wn = w & 1;
  const int m0 = blockIdx.x * 128, n0 = blockIdx.y * 128;

  // staging addresses: chunk c covers elements e = tid + 256c of 1024 16B-chunks
  const u16* aSrc[4];
  const u16* bSrc[4];
  int wOff[4];
#pragma unroll
  for (int c = 0; c < 4; c++) {
    int e = tid + 256 * c;
    int row = e >> 3, sl = e & 7;
    int am = m0 + row; if (am > M - 1) am = M - 1;
    aSrc[c] = A + (size_t)am * K + sl * 8;
    bSrc[c] = Bw + (size_t)(n0 + row) * K + sl * 8;
    wOff[c] = swzb(row, sl * 16);
  }

  f32x4 acc[4][4] = {};
  const int nkt = K >> 6;

  s16x8 rA[4], rB[4];
#pragma unroll
  for (int c = 0; c < 4; c++) {
    rA[c] = *(const s16x8*)aSrc[c];
    rB[c] = *(const s16x8*)bSrc[c];
  }

  for (int kt = 0; kt < nkt; kt++) {
    // write staged regs (compiler inserts counted vmcnt waits)
#pragma unroll
    for (int c = 0; c < 4; c++) {
      *(s16x8*)(smA + wOff[c]) = rA[c];
      *(s16x8*)(smB + wOff[c]) = rB[c];
    }
    // issue next tile's loads early (T14) — stay in flight across the barrier
    if (kt + 1 < nkt) {
      int k0 = (kt + 1) << 6;
#pragma unroll
      for (int c = 0; c < 4; c++) {
        rA[c] = *(const s16x8*)(aSrc[c] + k0);
        rB[c] = *(const s16x8*)(bSrc[c] + k0);
      }
    }
    asm volatile("s_waitcnt lgkmcnt(0)" ::: "memory");
    __builtin_amdgcn_s_barrier();
    __builtin_amdgcn_sched_barrier(0);
#pragma unroll
    for (int s = 0; s < 2; s++) {
      s16x8 af[4], bfr[4];
#pragma unroll
      for (int i = 0; i < 4; i++) {
        af[i] = *(const s16x8*)(smA + swzb(wm * 64 + i * 16 + l15, s * 64 + g * 16));
        bfr[i] = *(const s16x8*)(smB + swzb(wn * 64 + i * 16 + l15, s * 64 + g * 16));
      }
#pragma unroll
      for (int i = 0; i < 4; i++)
#pragma unroll
        for (int j = 0; j < 4; j++)
          acc[i][j] = mfma16(__builtin_bit_cast(bf16x8, af[i]),
                             __builtin_bit_cast(bf16x8, bfr[j]), acc[i][j]);
    }
    asm volatile("s_waitcnt lgkmcnt(0)" ::: "memory");
    __builtin_amdgcn_s_barrier();
    __builtin_amdgcn_sched_barrier(0);
  }

#pragma unroll
  for (int i = 0; i < 4; i++) {
#pragma unroll
    for (int j = 0; j < 4; j++) {
      int gmBase = m0 + wm * 64 + i * 16 + g * 4;
      int gn = n0 + wn * 64 + j * 16 + l15;
      float bs = bias[gn];
#pragma unroll
      for (int r = 0; r < 4; r++) {
        int gm = gmBase + r;
        if (gm >= M) continue;
        float v = acc[i][j][r] + bs;
        if (mode == 0) {
          obf[((size_t)(gn >> 5) * M + gm) * 32 + (gn & 31)] = f2bf(v);
        } else if (mode == 1) {
          obf[(size_t)gm * N + gn] = f2bf(v * scale);
        } else if (mode == 2) {
          of32[(size_t)gm * N + gn] += gamma[gn] * v;
        } else {
          obf[(size_t)gm * N + gn] = f2bf(0.5f * v * (1.f + erff(v * 0.70710678118654752f)));
        }
      }
    }
  }
}

// ---------------- MFMA flash attention (R2-proven) ----------------
__global__ __launch_bounds__(256) void k_attn(const u16* __restrict__ qb,
                                              const u16* __restrict__ kvb,
                                              u16* __restrict__ obf) {
  __shared__ u16 VtS[4][32][36];
  __shared__ uint32_t Pbuf[4][16][20];
  __shared__ float maccS[4][2560];
  __shared__ float mlS[4][160];

  const int bid = blockIdx.x;
  const int b = bid & 63, h = bid >> 6;
  const int tid = threadIdx.x, lane = tid & 63, w = tid >> 6;
  const int l15 = lane & 15, g = lane >> 4;

  const u16* Kp = kvb + ((size_t)h * 134400 + (size_t)b * 2100) * 32;
  const u16* Vp = kvb + ((size_t)(8 + h) * 134400 + (size_t)b * 2100) * 32;

  bf16x8 bq[5];
#pragma unroll
  for (int qt = 0; qt < 5; qt++) {
    int q = qt * 16 + l15; if (q > 74) q = 74;
    s16x8 qv = *(const s16x8*)(qb + (size_t)(b * 75 + q) * 256 + h * 32 + g * 8);
    bq[qt] = __builtin_bit_cast(bf16x8, qv);
  }

  f32x4 acc[5][2] = {};
  float mlc[5], llc[5];
#pragma unroll
  for (int qt = 0; qt < 5; qt++) { mlc[qt] = -1e30f; llc[qt] = 0.f; }

  s16x8 kfA, kfB, vvA, vvB;
  {
    int t0 = w * 32;
    int ta = t0 + l15; if (ta > 2099) ta = 2099;
    int tb = t0 + 16 + l15; if (tb > 2099) tb = 2099;
    kfA = *(const s16x8*)(Kp + (size_t)ta * 32 + g * 8);
    kfB = *(const s16x8*)(Kp + (size_t)tb * 32 + g * 8);
    int tga = t0 + (lane >> 2); if (tga > 2099) tga = 2099;
    int tgb = t0 + ((lane + 64) >> 2); if (tgb > 2099) tgb = 2099;
    vvA = *(const s16x8*)(Vp + (size_t)tga * 32 + (lane & 3) * 8);
    vvB = *(const s16x8*)(Vp + (size_t)tgb * 32 + (lane & 3) * 8);
  }

  for (int tt = w; tt < 66; tt += 4) {
    const int t0 = tt * 32;
    {
      u16* d0 = &VtS[w][lane >> 2][(lane & 3) * 8];
      u16* d1 = &VtS[w][(lane + 64) >> 2][(lane & 3) * 8];
#pragma unroll
      for (int e = 0; e < 8; e++) d0[e] = (u16)vvA[e];
#pragma unroll
      for (int e = 0; e < 8; e++) d1[e] = (u16)vvB[e];
    }
    bf16x8 bA = __builtin_bit_cast(bf16x8, kfA);
    bf16x8 bB = __builtin_bit_cast(bf16x8, kfB);
    s16x8 v0, v1;
#pragma unroll
    for (int e = 0; e < 8; e++) {
      v0[e] = (short)VtS[w][8 * g + e][l15];
      v1[e] = (short)VtS[w][8 * g + e][16 + l15];
    }
    bf16x8 bv0 = __builtin_bit_cast(bf16x8, v0);
    bf16x8 bv1 = __builtin_bit_cast(bf16x8, v1);
    int tn = tt + 4;
    if (tn < 66) {
      int t0n = tn * 32;
      int ta = t0n + l15; if (ta > 2099) ta = 2099;
      int tb = t0n + 16 + l15; if (tb > 2099) tb = 2099;
      kfA = *(const s16x8*)(Kp + (size_t)ta * 32 + g * 8);
      kfB = *(const s16x8*)(Kp + (size_t)tb * 32 + g * 8);
      int tga = t0n + (lane >> 2); if (tga > 2099) tga = 2099;
      int tgb = t0n + ((lane + 64) >> 2); if (tgb > 2099) tgb = 2099;
      vvA = *(const s16x8*)(Vp + (size_t)tga * 32 + (lane & 3) * 8);
      vvB = *(const s16x8*)(Vp + (size_t)tgb * 32 + (lane & 3) * 8);
    }
    const bool lastTile = (t0 == 2080);

#pragma unroll
    for (int qt = 0; qt < 5; qt++) {
      f32x4 z = {0.f, 0.f, 0.f, 0.f};
      f32x4 sA = mfma16(bA, bq[qt], z);
      f32x4 sB = mfma16(bB, bq[qt], z);
      if (lastTile && g >= 1) {
        sB[0] = sB[1] = sB[2] = sB[3] = -1e30f;
      }
      float px = fmaxf(fmaxf(fmaxf(sA[0], sA[1]), fmaxf(sA[2], sA[3])),
                       fmaxf(fmaxf(sB[0], sB[1]), fmaxf(sB[2], sB[3])));
      px = fmaxf(px, __shfl_xor(px, 16, 64));
      px = fmaxf(px, __shfl_xor(px, 32, 64));
      float mq = mlc[qt];
      if (!__all(px <= mq + 8.f)) {
        float mn = fmaxf(mq, px);
        float rs = exp2f(mq - mn);
        mlc[qt] = mn;
        llc[qt] *= rs;
#pragma unroll
        for (int r = 0; r < 4; r++) {
          float rr = __shfl(rs, ((lane >> 4) << 2) + r, 64);
          acc[qt][0][r] *= rr;
          acc[qt][1][r] *= rr;
        }
        mq = mn;
      }
      f32x4 pA, pB;
#pragma unroll
      for (int r = 0; r < 4; r++) {
        pA[r] = exp2f(sA[r] - mq);
        pB[r] = exp2f(sB[r] - mq);
      }
      float ps = pA[0] + pA[1] + pA[2] + pA[3] + pB[0] + pB[1] + pB[2] + pB[3];
      ps += __shfl_xor(ps, 16, 64);
      ps += __shfl_xor(ps, 32, 64);
      llc[qt] += ps;
      uint32_t* Pu = &Pbuf[w][l15][0];
      Pu[2 * g]     = pkbf(pA[0], pA[1]);
      Pu[2 * g + 1] = pkbf(pA[2], pA[3]);
      Pu[8 + 2 * g]     = pkbf(pB[0], pB[1]);
      Pu[8 + 2 * g + 1] = pkbf(pB[2], pB[3]);
      uint4 pu = *(const uint4*)&Pbuf[w][l15][4 * g];
      bf16x8 bp = __builtin_bit_cast(bf16x8, pu);
      acc[qt][0] = mfma16(bp, bv0, acc[qt][0]);
      acc[qt][1] = mfma16(bp, bv1, acc[qt][1]);
    }
  }

#pragma unroll
  for (int qt = 0; qt < 5; qt++)
#pragma unroll
    for (int dh = 0; dh < 2; dh++)
#pragma unroll
      for (int r = 0; r < 4; r++) {
        int q = qt * 16 + 4 * g + r;
        maccS[w][q * 32 + dh * 16 + l15] = acc[qt][dh][r];
      }
  if (lane < 16) {
#pragma unroll
    for (int qt = 0; qt < 5; qt++) {
      mlS[w][qt * 16 + l15] = mlc[qt];
      mlS[w][80 + qt * 16 + l15] = llc[qt];
    }
  }
  __syncthreads();

  for (int idx = tid; idx < 2400; idx += 256) {
    int q = idx >> 5, d = idx & 31;
    float M = -1e30f;
#pragma unroll
    for (int ww = 0; ww < 4; ww++) M = fmaxf(M, mlS[ww][q]);
    float L = 0.f, O = 0.f;
#pragma unroll
    for (int ww = 0; ww < 4; ww++) {
      float sc = exp2f(mlS[ww][q] - M);
      L += mlS[ww][80 + q] * sc;
      O += maccS[ww][q * 32 + d] * sc;
    }
    obf[(size_t)(b * 75 + q) * 256 + h * 32 + d] = f2bf(O / L);
  }
}

// ---------------- host ----------------
extern "C" void kernel_launch(void* const* d_in, const int* in_sizes, int n_in,
                              void* d_out, int out_size, void* d_ws, size_t ws_size,
                              hipStream_t stream) {
  const float* x_cls   = (const float*)d_in[0];
  const float* x_patch = (const float*)d_in[1];
  const float* ln1_w   = (const float*)d_in[2];
  const float* ln1_b   = (const float*)d_in[3];
  const float* q_w     = (const float*)d_in[4];
  const float* k_w     = (const float*)d_in[5];
  const float* v_w     = (const float*)d_in[6];
  const float* proj_w  = (const float*)d_in[7];
  const float* proj_b  = (const float*)d_in[8];
  const float* ln2_w   = (const float*)d_in[9];
  const float* ln2_b   = (const float*)d_in[10];
  const float* fc1_w   = (const float*)d_in[11];
  const float* fc1_b   = (const float*)d_in[12];
  const float* fc2_w   = (const float*)d_in[13];
  const float* fc2_b   = (const float*)d_in[14];
  const float* gamma1  = (const float*)d_in[15];
  const float* gamma2  = (const float*)d_in[16];
  float* xc = (float*)d_out;

  char* ws = (char*)d_ws;
  size_t off = 0;
  auto alloc = [&](size_t bytes) {
    char* p = ws + off;
    off += (bytes + 255) & ~(size_t)255;
    return p;
  };
  u16* nx    = (u16*)alloc(134400ull * 256 * 2);
  u16* uncls = (u16*)alloc(4800ull * 256 * 2);
  u16* kvb   = (u16*)alloc(134400ull * 512 * 2);
  u16* qb    = (u16*)alloc(4800ull * 256 * 2);
  u16* ob    = (u16*)alloc(4800ull * 256 * 2);
  u16* xn    = (u16*)alloc(4800ull * 256 * 2);
  u16* hb    = (u16*)alloc(4800ull * 1024 * 2);
  u16* qp    = (u16*)alloc(2ull * 65536 * 2);
  u16* kvp   = (u16*)alloc(2ull * 131072 * 2);
  u16* pjp   = (u16*)alloc(2ull * 65536 * 2);
  u16* f1p   = (u16*)alloc(2ull * 262144 * 2);
  u16* f2p   = (u16*)alloc(2ull * 262144 * 2);
  float* bias_kv = (float*)alloc(2ull * 512 * 4);
  float* bias_q  = (float*)alloc(2ull * 256 * 4);
  float* bias_f1 = (float*)alloc(2ull * 1024 * 4);

  k_copy<<<1200, 256, 0, stream>>>(x_cls, xc, 307200);
  for (int i = 0; i < 2; i++) {
    k_fold<<<64, 256, 0, stream>>>(k_w + i * 65536, ln1_w + i * 256, ln1_b + i * 256,
                                   nullptr, kvp + i * 131072, bias_kv + i * 512, 256);
    k_fold<<<64, 256, 0, stream>>>(v_w + i * 65536, ln1_w + i * 256, ln1_b + i * 256,
                                   nullptr, kvp + i * 131072 + 65536, bias_kv + i * 512 + 256, 256);
    k_fold<<<64, 256, 0, stream>>>(q_w + i * 65536, ln1_w + i * 256, ln1_b + i * 256,
                                   nullptr, qp + i * 65536, bias_q + i * 256, 256);
    k_fold<<<256, 256, 0, stream>>>(fc1_w + i * 262144, ln2_w + i * 256, ln2_b + i * 256,
                                    fc1_b + i * 1024, f1p + i * 262144, bias_f1 + i * 1024, 1024);
    k_cast4<<<64, 256, 0, stream>>>(proj_w + i * 65536, pjp + i * 65536, 16384);
    k_cast4<<<256, 256, 0, stream>>>(fc2_w + i * 262144, f2p + i * 262144, 65536);
  }
  // normalize patch tokens ONCE (identical across both CA blocks)
  k_norm<<<32400, 256, 0, stream>>>(x_patch, nx, nullptr, 1, 129600);

  const float qscale = 0.25503489f;  // 1/sqrt(32) * log2(e)
  for (int i = 0; i < 2; i++) {
    k_norm<<<1200, 256, 0, stream>>>(xc, nx, uncls, 0, 4800);
    dim3 gkv(1050, 4);
    k_gemm3<<<gkv, 256, 0, stream>>>(nx, kvp + i * 131072, 134400, 512, 256, 0, 0.f,
                                     bias_kv + i * 512, nullptr, kvb, nullptr);
    dim3 gq(38, 2);
    k_gemm3<<<gq, 256, 0, stream>>>(uncls, qp + i * 65536, 4800, 256, 256, 1, qscale,
                                    bias_q + i * 256, nullptr, qb, nullptr);
    k_attn<<<512, 256, 0, stream>>>(qb, kvb, ob);
    k_gemm3<<<gq, 256, 0, stream>>>(ob, pjp + i * 65536, 4800, 256, 256, 2, 0.f,
                                    proj_b + i * 256, gamma1 + i * 256, nullptr, xc);
    k_norm<<<1200, 256, 0, stream>>>(xc, nullptr, xn, 2, 4800);
    dim3 gf1(38, 8);
    k_gemm3<<<gf1, 256, 0, stream>>>(xn, f1p + i * 262144, 4800, 1024, 256, 3, 0.f,
                                     bias_f1 + i * 1024, nullptr, hb, nullptr);
    k_gemm3<<<gq, 256, 0, stream>>>(hb, f2p + i * 262144, 4800, 256, 1024, 2, 0.f,
                                    fc2_b + i * 256, gamma2 + i * 256, nullptr, xc);
  }
}